// Round 2
// baseline (324.212 us; speedup 1.0000x reference)
//
#include <hip/hip_runtime.h>

#define Hdim 512
#define Wdim 512
#define Cdim 256
#define OUTH 7
#define OUTW 7
#define SW 513   // padded widths of integral image S: [H+1][W+1][C]
#define SH 513
#define NROI_BINS (OUTH * OUTW)
#define NSEG 4          // segments along each scan axis
#define SEGLEN 128      // 512 / NSEG

static constexpr size_t S_ELEMS = (size_t)SH * SW * Cdim;            // 67,371,264
static constexpr size_t T_ELEMS = (size_t)NSEG * Wdim * Cdim;        // 524,288 (col-seg totals / offsets)
static constexpr size_t U_ELEMS = (size_t)SH * NSEG * Cdim;          // 525,312 (row-seg totals / offsets)
static constexpr size_t WS_NEED = (S_ELEMS + T_ELEMS + U_ELEMS) * sizeof(float);

// ---------------- K1: segmented column cumsum (along H), f64 accumulate ----
// grid (Wdim, NSEG) x 64 threads; thread = c-quad. Writes segment-local
// colcum into S rows [seg*128+1 .. seg*128+128], and segment totals to T.
// seg==0 blocks also zero pad row 0.
__global__ void colcum_seg(const float* __restrict__ x, float* __restrict__ S,
                           float* __restrict__ T) {
    const int w   = blockIdx.x;      // 0..511
    const int seg = blockIdx.y;      // 0..3
    const int c   = threadIdx.x * 4; // 0,4,..,252

    if (seg == 0) {  // zero pad row 0: SW*Cdim floats = 32832 quads
        const float4 z = {0.f, 0.f, 0.f, 0.f};
        const size_t nq = (size_t)SW * (Cdim / 4);
        for (size_t q = (size_t)w * 64 + threadIdx.x; q < nq; q += (size_t)Wdim * 64)
            reinterpret_cast<float4*>(S)[q] = z;
    }

    const int h0 = seg * SEGLEN;
    const float* xp = x + ((size_t)h0 * Wdim + w) * Cdim + c;
    float* sp = S + ((size_t)(h0 + 1) * SW + (w + 1)) * Cdim + c;

    double a0 = 0, a1 = 0, a2 = 0, a3 = 0;
    for (int hh = 0; hh < SEGLEN; hh += 8) {
        float4 v[8];
        #pragma unroll
        for (int k = 0; k < 8; ++k)
            v[k] = *reinterpret_cast<const float4*>(xp + (size_t)(hh + k) * (Wdim * Cdim));
        #pragma unroll
        for (int k = 0; k < 8; ++k) {
            a0 += v[k].x; a1 += v[k].y; a2 += v[k].z; a3 += v[k].w;
            float4 o = {(float)a0, (float)a1, (float)a2, (float)a3};
            *reinterpret_cast<float4*>(sp + (size_t)(hh + k) * (SW * Cdim)) = o;
        }
    }
    float4 t = {(float)a0, (float)a1, (float)a2, (float)a3};
    *reinterpret_cast<float4*>(T + ((size_t)seg * Wdim + w) * Cdim + c) = t;
}

// ---------------- K1b: exclusive prefix of T along seg, in place -----------
__global__ void prefix_T(float* __restrict__ T) {
    const int w = blockIdx.x;
    const int c = threadIdx.x * 4;
    float4 acc = {0.f, 0.f, 0.f, 0.f};
    #pragma unroll
    for (int s = 0; s < NSEG; ++s) {
        float4* p = reinterpret_cast<float4*>(T + ((size_t)s * Wdim + w) * Cdim + c);
        float4 v = *p;
        *p = acc;
        acc.x += v.x; acc.y += v.y; acc.z += v.z; acc.w += v.w;
    }
}

// ---------------- K2: segmented row cumsum (along W), adds col offsets ------
// grid (Hdim, NSEG) x 64 threads; block (h, wseg) scans w in [wseg*128, +128),
// value = S_k1[h+1][w+1] + O[hseg(h)][w]; writes segment-local rowcum back to
// S and the segment total to U[h+1][wseg]. wseg==0 blocks zero pad col 0.
__global__ void rowcum_seg(float* __restrict__ S, const float* __restrict__ O,
                           float* __restrict__ U) {
    const int h  = blockIdx.x;       // 0..511 (original row; padded row h+1)
    const int ws = blockIdx.y;       // 0..3
    const int c  = threadIdx.x * 4;
    const int hseg = h >> 7;

    float* sp = S + (size_t)(h + 1) * SW * Cdim + c;          // col 0 of padded row
    const float* op = O + (size_t)hseg * Wdim * Cdim + c;

    if (ws == 0) {
        const float4 z = {0.f, 0.f, 0.f, 0.f};
        *reinterpret_cast<float4*>(sp) = z;                   // pad col 0
    }

    const int w0 = ws * SEGLEN;
    double a0 = 0, a1 = 0, a2 = 0, a3 = 0;
    for (int wwb = 0; wwb < SEGLEN; wwb += 8) {
        float4 v[8], o[8];
        #pragma unroll
        for (int k = 0; k < 8; ++k) {
            const int w = w0 + wwb + k;
            v[k] = *reinterpret_cast<const float4*>(sp + (size_t)(w + 1) * Cdim);
            o[k] = *reinterpret_cast<const float4*>(op + (size_t)w * Cdim);
        }
        #pragma unroll
        for (int k = 0; k < 8; ++k) {
            const int w = w0 + wwb + k;
            a0 += (double)v[k].x + (double)o[k].x;
            a1 += (double)v[k].y + (double)o[k].y;
            a2 += (double)v[k].z + (double)o[k].z;
            a3 += (double)v[k].w + (double)o[k].w;
            float4 r = {(float)a0, (float)a1, (float)a2, (float)a3};
            *reinterpret_cast<float4*>(sp + (size_t)(w + 1) * Cdim) = r;
        }
    }
    float4 t = {(float)a0, (float)a1, (float)a2, (float)a3};
    *reinterpret_cast<float4*>(U + ((size_t)(h + 1) * NSEG + ws) * Cdim + c) = t;
}

// ---------------- K2b: exclusive prefix of U along wseg, in place ----------
__global__ void prefix_U(float* __restrict__ U) {
    const int h = blockIdx.x + 1;    // padded rows 1..512
    const int c = threadIdx.x * 4;
    float4 acc = {0.f, 0.f, 0.f, 0.f};
    #pragma unroll
    for (int s = 0; s < NSEG; ++s) {
        float4* p = reinterpret_cast<float4*>(U + ((size_t)h * NSEG + s) * Cdim + c);
        float4 v = *p;
        *p = acc;
        acc.x += v.x; acc.y += v.y; acc.z += v.z; acc.w += v.w;
    }
}

// ---------------- shared bin-edge math (replicates reference exactly) ------
__device__ __forceinline__ void roi_bounds(const float4 r, int& hs, int& ws,
                                           int& rh, int& rw) {
    hs = (int)floorf((float)Hdim * r.x);
    ws = (int)floorf((float)Wdim * r.y);
    int he = (int)floorf((float)Hdim * r.z);
    int we = (int)floorf((float)Wdim * r.w);
    he = max(he, hs + 1);
    we = max(we, ws + 1);
    rh = he - hs;
    rw = we - ws;
}

// ---------------- K3: gather 4 corners per bin ------------------------------
// Corner value = S[hb][wb] + Uprefix[hb][(wb-1)>>7] (0 if hb==0 or wb==0).
__global__ void gather_kernel(const float* __restrict__ S,
                              const float* __restrict__ U,
                              const float* __restrict__ rois,
                              float* __restrict__ out, int N) {
    const int n = blockIdx.x / OUTH;
    const int i = blockIdx.x % OUTH;
    const int c = threadIdx.x;
    if (n >= N) return;

    const float4 r = reinterpret_cast<const float4*>(rois)[n];  // y0,x0,y1,x1
    int hs, ws, rh, rw;
    roi_bounds(r, hs, ws, rh, rw);

    const int hb0 = hs + (i * rh) / OUTH;
    const int hb1 = hs + ((i + 1) * rh + OUTH - 1) / OUTH;   // ceil div
    const float dh = (float)(hb1 - hb0);

    const float* S0 = S + (size_t)hb0 * (SW * Cdim) + c;
    const float* S1 = S + (size_t)hb1 * (SW * Cdim) + c;
    const float* U0 = U + (size_t)hb0 * (NSEG * Cdim) + c;
    const float* U1 = U + (size_t)hb1 * (NSEG * Cdim) + c;
    float* op = out + ((size_t)(n * OUTH + i) * OUTW) * Cdim + c;

    // hb1 >= 1 always; hb0 may be 0.
    const bool r0 = (hb0 > 0);

    #pragma unroll
    for (int j = 0; j < OUTW; ++j) {
        const int wb0 = ws + (j * rw) / OUTW;
        const int wb1 = ws + ((j + 1) * rw + OUTW - 1) / OUTW;
        const int sg1 = (wb1 - 1) >> 7;          // wb1 >= 1 always
        const float s11 = S1[(size_t)wb1 * Cdim] + U1[(size_t)sg1 * Cdim];
        float s01 = 0.f, s10 = 0.f, s00 = 0.f;
        if (r0) s01 = S0[(size_t)wb1 * Cdim] + U0[(size_t)sg1 * Cdim];
        if (wb0 > 0) {
            const int sg0 = (wb0 - 1) >> 7;
            s10 = S1[(size_t)wb0 * Cdim] + U1[(size_t)sg0 * Cdim];
            if (r0) s00 = S0[(size_t)wb0 * Cdim] + U0[(size_t)sg0 * Cdim];
        }
        const float area = dh * (float)(wb1 - wb0);
        op[(size_t)j * Cdim] = (((s11 - s01) - s10) + s00) / area;
    }
}

// ---------------- Fallback: direct per-bin summation (ws too small) --------
__global__ void direct_kernel(const float* __restrict__ x,
                              const float* __restrict__ rois,
                              float* __restrict__ out, int N) {
    const int bid = blockIdx.x;
    const int n = bid / NROI_BINS;
    const int rem = bid % NROI_BINS;
    const int i = rem / OUTW;
    const int j = rem % OUTW;
    const int c = threadIdx.x;
    if (n >= N) return;

    const float4 r = reinterpret_cast<const float4*>(rois)[n];
    int hs, ws, rh, rw;
    roi_bounds(r, hs, ws, rh, rw);

    const int hb0 = hs + (i * rh) / OUTH;
    const int hb1 = hs + ((i + 1) * rh + OUTH - 1) / OUTH;
    const int wb0 = ws + (j * rw) / OUTW;
    const int wb1 = ws + ((j + 1) * rw + OUTW - 1) / OUTW;

    double acc = 0.0;
    for (int h = hb0; h < hb1; ++h) {
        const float* xp = x + ((size_t)h * Wdim) * Cdim + c;
        for (int w = wb0; w < wb1; ++w)
            acc += (double)xp[(size_t)w * Cdim];
    }
    const float area = (float)((hb1 - hb0) * (wb1 - wb0));
    out[((size_t)bid) * Cdim + c] = (float)(acc / (double)area);
}

extern "C" void kernel_launch(void* const* d_in, const int* in_sizes, int n_in,
                              void* d_out, int out_size, void* d_ws, size_t ws_size,
                              hipStream_t stream) {
    const float* x    = (const float*)d_in[0];
    const float* rois = (const float*)d_in[1];
    float* out        = (float*)d_out;
    const int N       = in_sizes[1] / 4;   // 2000

    if (ws_size >= WS_NEED) {
        float* S = (float*)d_ws;
        float* T = S + S_ELEMS;
        float* U = T + T_ELEMS;
        colcum_seg<<<dim3(Wdim, NSEG), 64, 0, stream>>>(x, S, T);
        prefix_T<<<Wdim, 64, 0, stream>>>(T);
        rowcum_seg<<<dim3(Hdim, NSEG), 64, 0, stream>>>(S, T, U);
        prefix_U<<<Hdim, 64, 0, stream>>>(U);
        gather_kernel<<<N * OUTH, Cdim, 0, stream>>>(S, U, rois, out, N);
    } else {
        direct_kernel<<<N * NROI_BINS, Cdim, 0, stream>>>(x, rois, out, N);
    }
}

// Round 3
// 274.463 us; speedup vs baseline: 1.1813x; 1.1813x over previous
//
#include <hip/hip_runtime.h>

#define Hdim 512
#define Wdim 512
#define Cdim 256
#define OUTH 7
#define OUTW 7
#define TS 16            // tile edge
#define NT 32            // tiles per dim = 512/16
#define NROI_BINS (OUTH * OUTW)

static constexpr size_t SLOC_ELEMS = (size_t)Hdim * Wdim * Cdim;   // 67,108,864 (~268 MB)
static constexpr size_t EL_ELEMS   = (size_t)Hdim * NT * Cdim;     // 4,194,304  (~17 MB)
static constexpr size_t F_ELEMS    = (size_t)NT * Wdim * Cdim;     // 4,194,304  (~17 MB)
static constexpr size_t WS_NEED    = (SLOC_ELEMS + EL_ELEMS + F_ELEMS) * sizeof(float);

// ---------------- K1: per-tile local 2D SAT ---------------------------------
// grid 1024 blocks (tile tI,tJ) x 256 threads (c). Each block computes the
// 16x16 tile-local inclusive SAT for all 256 channels. Double-buffered row
// prefetch; all array indices compile-time (full unroll).
__global__ void local_sat(const float* __restrict__ x, float* __restrict__ Sloc) {
    const int tI = blockIdx.x >> 5;
    const int tJ = blockIdx.x & 31;
    const int c  = threadIdx.x;

    const size_t base = ((size_t)(tI * TS) * Wdim + (size_t)(tJ * TS)) * Cdim + c;
    const float* xp = x + base;
    float* sp = Sloc + base;

    float P[TS];
    #pragma unroll
    for (int w = 0; w < TS; ++w) P[w] = 0.f;

    float va[TS], vb[TS];
    #pragma unroll
    for (int w = 0; w < TS; ++w) va[w] = xp[(size_t)w * Cdim];   // row 0

    #pragma unroll
    for (int h = 0; h < TS; ++h) {
        const float* cur = (h & 1) ? vb : va;
        float*       nxt = (h & 1) ? va : vb;
        if (h + 1 < TS) {
            #pragma unroll
            for (int w = 0; w < TS; ++w)
                nxt[w] = xp[((size_t)(h + 1) * Wdim + w) * Cdim];
        }
        float rowAcc = 0.f;
        #pragma unroll
        for (int w = 0; w < TS; ++w) {
            rowAcc += cur[w];
            P[w] += rowAcc;
            sp[((size_t)h * Wdim + w) * Cdim] = P[w];
        }
    }
}

// ---------------- K2a: E_left[h][J][c] = sum_{J'<J} Sloc[h][16J'+15][c] -----
// grid 512 blocks (h) x 256 threads (c); exclusive prefix, f64 accumulate.
__global__ void make_eleft(const float* __restrict__ Sloc, float* __restrict__ EL) {
    const int h = blockIdx.x;
    const int c = threadIdx.x;
    const float* sp = Sloc + (size_t)h * Wdim * Cdim + c;
    float* ep = EL + (size_t)h * NT * Cdim + c;

    double acc = 0.0;
    #pragma unroll 8
    for (int J = 0; J < NT; ++J) {
        const float t = sp[(size_t)(J * TS + TS - 1) * Cdim];
        ep[(size_t)J * Cdim] = (float)acc;
        acc += (double)t;
    }
}

// ---------------- K2b: F[I][w][c] = sum_{I'<I} (Sloc[16I'+15][w][c]
//                                               + EL[16I'+15][w>>4][c]) ------
// grid 512 blocks (w) x 256 threads (c); exclusive prefix, f64 accumulate.
__global__ void make_f(const float* __restrict__ Sloc, const float* __restrict__ EL,
                       float* __restrict__ F) {
    const int w = blockIdx.x;
    const int c = threadIdx.x;
    const int J = w >> 4;
    const float* sp = Sloc + (size_t)w * Cdim + c;
    const float* ep = EL + (size_t)J * Cdim + c;
    float* fp = F + (size_t)w * Cdim + c;

    double acc = 0.0;
    #pragma unroll 8
    for (int I = 0; I < NT; ++I) {
        const int hb = I * TS + TS - 1;
        const float a = sp[(size_t)hb * Wdim * Cdim];
        const float b = ep[(size_t)hb * NT * Cdim];
        fp[(size_t)I * Wdim * Cdim] = (float)acc;
        acc += (double)a + (double)b;
    }
}

// ---------------- shared bin-edge math (replicates reference exactly) ------
__device__ __forceinline__ void roi_bounds(const float4 r, int& hs, int& ws,
                                           int& rh, int& rw) {
    hs = (int)floorf((float)Hdim * r.x);
    ws = (int)floorf((float)Wdim * r.y);
    int he = (int)floorf((float)Hdim * r.z);
    int we = (int)floorf((float)Wdim * r.w);
    he = max(he, hs + 1);
    we = max(we, ws + 1);
    rh = he - hs;
    rw = we - ws;
}

// Corner of the padded integral image at (hb, wb) in [0,512]^2:
// 0 if on the pad; else absolute SAT at (hb-1, wb-1) reconstructed from the
// 3-term hierarchical decomposition.
__device__ __forceinline__ float corner_val(const float* __restrict__ Sloc,
                                            const float* __restrict__ EL,
                                            const float* __restrict__ F,
                                            int hb, int wb, int c) {
    if (hb == 0 || wb == 0) return 0.f;   // block-uniform branch
    const int h = hb - 1, w = wb - 1;
    const int I = h >> 4, J = w >> 4;
    return Sloc[((size_t)h * Wdim + w) * Cdim + c]
         + F[((size_t)I * Wdim + w) * Cdim + c]
         + EL[((size_t)h * NT + J) * Cdim + c];
}

// ---------------- K3: gather 4 corners per bin -------------------------------
// grid (N * OUTH) blocks x 256 threads (c). Block = (roi n, out-row i).
__global__ void gather_kernel(const float* __restrict__ Sloc,
                              const float* __restrict__ EL,
                              const float* __restrict__ F,
                              const float* __restrict__ rois,
                              float* __restrict__ out, int N) {
    const int n = blockIdx.x / OUTH;
    const int i = blockIdx.x % OUTH;
    const int c = threadIdx.x;
    if (n >= N) return;

    const float4 r = reinterpret_cast<const float4*>(rois)[n];  // y0,x0,y1,x1
    int hs, ws, rh, rw;
    roi_bounds(r, hs, ws, rh, rw);

    const int hb0 = hs + (i * rh) / OUTH;
    const int hb1 = hs + ((i + 1) * rh + OUTH - 1) / OUTH;   // ceil div
    const float dh = (float)(hb1 - hb0);

    float* op = out + ((size_t)(n * OUTH + i) * OUTW) * Cdim + c;

    #pragma unroll
    for (int j = 0; j < OUTW; ++j) {
        const int wb0 = ws + (j * rw) / OUTW;
        const int wb1 = ws + ((j + 1) * rw + OUTW - 1) / OUTW;
        const float s11 = corner_val(Sloc, EL, F, hb1, wb1, c);
        const float s01 = corner_val(Sloc, EL, F, hb0, wb1, c);
        const float s10 = corner_val(Sloc, EL, F, hb1, wb0, c);
        const float s00 = corner_val(Sloc, EL, F, hb0, wb0, c);
        const float area = dh * (float)(wb1 - wb0);
        op[(size_t)j * Cdim] = (((s11 - s01) - s10) + s00) / area;
    }
}

// ---------------- Fallback: direct per-bin summation (ws too small) --------
__global__ void direct_kernel(const float* __restrict__ x,
                              const float* __restrict__ rois,
                              float* __restrict__ out, int N) {
    const int bid = blockIdx.x;
    const int n = bid / NROI_BINS;
    const int rem = bid % NROI_BINS;
    const int i = rem / OUTW;
    const int j = rem % OUTW;
    const int c = threadIdx.x;
    if (n >= N) return;

    const float4 r = reinterpret_cast<const float4*>(rois)[n];
    int hs, ws, rh, rw;
    roi_bounds(r, hs, ws, rh, rw);

    const int hb0 = hs + (i * rh) / OUTH;
    const int hb1 = hs + ((i + 1) * rh + OUTH - 1) / OUTH;
    const int wb0 = ws + (j * rw) / OUTW;
    const int wb1 = ws + ((j + 1) * rw + OUTW - 1) / OUTW;

    double acc = 0.0;
    for (int h = hb0; h < hb1; ++h) {
        const float* xp = x + ((size_t)h * Wdim) * Cdim + c;
        for (int w = wb0; w < wb1; ++w)
            acc += (double)xp[(size_t)w * Cdim];
    }
    const float area = (float)((hb1 - hb0) * (wb1 - wb0));
    out[((size_t)bid) * Cdim + c] = (float)(acc / (double)area);
}

extern "C" void kernel_launch(void* const* d_in, const int* in_sizes, int n_in,
                              void* d_out, int out_size, void* d_ws, size_t ws_size,
                              hipStream_t stream) {
    const float* x    = (const float*)d_in[0];
    const float* rois = (const float*)d_in[1];
    float* out        = (float*)d_out;
    const int N       = in_sizes[1] / 4;   // 2000

    if (ws_size >= WS_NEED) {
        float* Sloc = (float*)d_ws;
        float* EL   = Sloc + SLOC_ELEMS;
        float* F    = EL + EL_ELEMS;
        local_sat<<<NT * NT, Cdim, 0, stream>>>(x, Sloc);
        make_eleft<<<Hdim, Cdim, 0, stream>>>(Sloc, EL);
        make_f<<<Wdim, Cdim, 0, stream>>>(Sloc, EL, F);
        gather_kernel<<<N * OUTH, Cdim, 0, stream>>>(Sloc, EL, F, rois, out, N);
    } else {
        direct_kernel<<<N * NROI_BINS, Cdim, 0, stream>>>(x, rois, out, N);
    }
}

// Round 4
// 262.503 us; speedup vs baseline: 1.2351x; 1.0456x over previous
//
#include <hip/hip_runtime.h>

#define Hdim 512
#define Wdim 512
#define Cdim 256
#define OUTH 7
#define OUTW 7
#define TS 32            // tile edge
#define NT 16            // tiles per dim = 512/32
#define CG 64            // channels per K1 block
#define NROI_BINS (OUTH * OUTW)

static constexpr size_t SLOC_ELEMS = (size_t)Hdim * Wdim * Cdim;   // 67,108,864 (~268 MB)
static constexpr size_t EL_ELEMS   = (size_t)Hdim * NT * Cdim;     // 2,097,152  (~8.4 MB)
static constexpr size_t F_ELEMS    = (size_t)NT * Wdim * Cdim;     // 2,097,152  (~8.4 MB)
static constexpr size_t WS_NEED    = (SLOC_ELEMS + EL_ELEMS + F_ELEMS) * sizeof(float);

// ---------------- K1: per-tile local 2D SAT (32x32 tiles) -------------------
// grid 16*16*4 = 1024 blocks x 64 threads. Block = (tile tI,tJ, channel group
// cg of 64). Double-buffered row prefetch, all indices compile-time.
__global__ void local_sat(const float* __restrict__ x, float* __restrict__ Sloc) {
    const int cg = blockIdx.x & 3;
    const int tJ = (blockIdx.x >> 2) & (NT - 1);
    const int tI = blockIdx.x >> 6;
    const int c  = cg * CG + threadIdx.x;

    const size_t base = ((size_t)(tI * TS) * Wdim + (size_t)(tJ * TS)) * Cdim + c;
    const float* xp = x + base;
    float* sp = Sloc + base;

    float P[TS];
    #pragma unroll
    for (int w = 0; w < TS; ++w) P[w] = 0.f;

    float va[TS], vb[TS];
    #pragma unroll
    for (int w = 0; w < TS; ++w) va[w] = xp[(size_t)w * Cdim];   // row 0

    #pragma unroll
    for (int h = 0; h < TS; ++h) {
        const float* cur = (h & 1) ? vb : va;
        float*       nxt = (h & 1) ? va : vb;
        if (h + 1 < TS) {
            #pragma unroll
            for (int w = 0; w < TS; ++w)
                nxt[w] = xp[((size_t)(h + 1) * Wdim + w) * Cdim];
        }
        float rowAcc = 0.f;
        #pragma unroll
        for (int w = 0; w < TS; ++w) {
            rowAcc += cur[w];
            P[w] += rowAcc;
            sp[((size_t)h * Wdim + w) * Cdim] = P[w];
        }
    }
}

// ---------------- K2a: E_left[h][J][c] = sum_{J'<J} Sloc[h][32J'+31][c] -----
// grid 512 blocks (h) x 256 threads (c); exclusive prefix, f64 accumulate.
__global__ void make_eleft(const float* __restrict__ Sloc, float* __restrict__ EL) {
    const int h = blockIdx.x;
    const int c = threadIdx.x;
    const float* sp = Sloc + (size_t)h * Wdim * Cdim + c;
    float* ep = EL + (size_t)h * NT * Cdim + c;

    double acc = 0.0;
    #pragma unroll
    for (int J = 0; J < NT; ++J) {
        const float t = sp[(size_t)(J * TS + TS - 1) * Cdim];
        ep[(size_t)J * Cdim] = (float)acc;
        acc += (double)t;
    }
}

// ---------------- K2b: F[I][w][c] = sum_{I'<I} (Sloc[32I'+31][w][c]
//                                               + EL[32I'+31][w>>5][c]) ------
// grid 512 blocks (w) x 256 threads (c); exclusive prefix, f64 accumulate.
__global__ void make_f(const float* __restrict__ Sloc, const float* __restrict__ EL,
                       float* __restrict__ F) {
    const int w = blockIdx.x;
    const int c = threadIdx.x;
    const int J = w >> 5;
    const float* sp = Sloc + (size_t)w * Cdim + c;
    const float* ep = EL + (size_t)J * Cdim + c;
    float* fp = F + (size_t)w * Cdim + c;

    double acc = 0.0;
    #pragma unroll
    for (int I = 0; I < NT; ++I) {
        const int hb = I * TS + TS - 1;
        const float a = sp[(size_t)hb * Wdim * Cdim];
        const float b = ep[(size_t)hb * NT * Cdim];
        fp[(size_t)I * Wdim * Cdim] = (float)acc;
        acc += (double)a + (double)b;
    }
}

// ---------------- shared bin-edge math (replicates reference exactly) ------
__device__ __forceinline__ void roi_bounds(const float4 r, int& hs, int& ws,
                                           int& rh, int& rw) {
    hs = (int)floorf((float)Hdim * r.x);
    ws = (int)floorf((float)Wdim * r.y);
    int he = (int)floorf((float)Hdim * r.z);
    int we = (int)floorf((float)Wdim * r.w);
    he = max(he, hs + 1);
    we = max(we, ws + 1);
    rh = he - hs;
    rw = we - ws;
}

// Corner of the padded integral image at (hb, wb) in [0,512]^2.
// Sloc is a read-once random stream -> non-temporal load (don't evict F/EL).
__device__ __forceinline__ float corner_val(const float* __restrict__ Sloc,
                                            const float* __restrict__ EL,
                                            const float* __restrict__ F,
                                            int hb, int wb, int c) {
    if (hb == 0 || wb == 0) return 0.f;
    const int h = hb - 1, w = wb - 1;
    const int I = h >> 5, J = w >> 5;
    const float sl = __builtin_nontemporal_load(&Sloc[((size_t)h * Wdim + w) * Cdim + c]);
    return sl + F[((size_t)I * Wdim + w) * Cdim + c]
              + EL[((size_t)h * NT + J) * Cdim + c];
}

// ---------------- K3: gather 4 corners per bin -------------------------------
// grid (N * OUTH) blocks x 256 threads (c). Block = (roi n, out-row i).
__global__ void gather_kernel(const float* __restrict__ Sloc,
                              const float* __restrict__ EL,
                              const float* __restrict__ F,
                              const float* __restrict__ rois,
                              float* __restrict__ out, int N) {
    const int n = blockIdx.x / OUTH;
    const int i = blockIdx.x % OUTH;
    const int c = threadIdx.x;
    if (n >= N) return;

    const float4 r = reinterpret_cast<const float4*>(rois)[n];  // y0,x0,y1,x1
    int hs, ws, rh, rw;
    roi_bounds(r, hs, ws, rh, rw);

    const int hb0 = hs + (i * rh) / OUTH;
    const int hb1 = hs + ((i + 1) * rh + OUTH - 1) / OUTH;   // ceil div
    const float dh = (float)(hb1 - hb0);

    float* op = out + ((size_t)(n * OUTH + i) * OUTW) * Cdim + c;

    #pragma unroll
    for (int j = 0; j < OUTW; ++j) {
        const int wb0 = ws + (j * rw) / OUTW;
        const int wb1 = ws + ((j + 1) * rw + OUTW - 1) / OUTW;
        const float s11 = corner_val(Sloc, EL, F, hb1, wb1, c);
        const float s01 = corner_val(Sloc, EL, F, hb0, wb1, c);
        const float s10 = corner_val(Sloc, EL, F, hb1, wb0, c);
        const float s00 = corner_val(Sloc, EL, F, hb0, wb0, c);
        const float area = dh * (float)(wb1 - wb0);
        __builtin_nontemporal_store((((s11 - s01) - s10) + s00) / area,
                                    &op[(size_t)j * Cdim]);
    }
}

// ---------------- Fallback: direct per-bin summation (ws too small) --------
__global__ void direct_kernel(const float* __restrict__ x,
                              const float* __restrict__ rois,
                              float* __restrict__ out, int N) {
    const int bid = blockIdx.x;
    const int n = bid / NROI_BINS;
    const int rem = bid % NROI_BINS;
    const int i = rem / OUTW;
    const int j = rem % OUTW;
    const int c = threadIdx.x;
    if (n >= N) return;

    const float4 r = reinterpret_cast<const float4*>(rois)[n];
    int hs, ws, rh, rw;
    roi_bounds(r, hs, ws, rh, rw);

    const int hb0 = hs + (i * rh) / OUTH;
    const int hb1 = hs + ((i + 1) * rh + OUTH - 1) / OUTH;
    const int wb0 = ws + (j * rw) / OUTW;
    const int wb1 = ws + ((j + 1) * rw + OUTW - 1) / OUTW;

    double acc = 0.0;
    for (int h = hb0; h < hb1; ++h) {
        const float* xp = x + ((size_t)h * Wdim) * Cdim + c;
        for (int w = wb0; w < wb1; ++w)
            acc += (double)xp[(size_t)w * Cdim];
    }
    const float area = (float)((hb1 - hb0) * (wb1 - wb0));
    out[((size_t)bid) * Cdim + c] = (float)(acc / (double)area);
}

extern "C" void kernel_launch(void* const* d_in, const int* in_sizes, int n_in,
                              void* d_out, int out_size, void* d_ws, size_t ws_size,
                              hipStream_t stream) {
    const float* x    = (const float*)d_in[0];
    const float* rois = (const float*)d_in[1];
    float* out        = (float*)d_out;
    const int N       = in_sizes[1] / 4;   // 2000

    if (ws_size >= WS_NEED) {
        float* Sloc = (float*)d_ws;
        float* EL   = Sloc + SLOC_ELEMS;
        float* F    = EL + EL_ELEMS;
        local_sat<<<NT * NT * 4, CG, 0, stream>>>(x, Sloc);
        make_eleft<<<Hdim, Cdim, 0, stream>>>(Sloc, EL);
        make_f<<<Wdim, Cdim, 0, stream>>>(Sloc, EL, F);
        gather_kernel<<<N * OUTH, Cdim, 0, stream>>>(Sloc, EL, F, rois, out, N);
    } else {
        direct_kernel<<<N * NROI_BINS, Cdim, 0, stream>>>(x, rois, out, N);
    }
}

// Round 6
// 237.277 us; speedup vs baseline: 1.3664x; 1.1063x over previous
//
#include <hip/hip_runtime.h>

#define Hdim 512
#define Wdim 512
#define Cdim 256
#define CQ 64            // Cdim/4 float4 quads per line
#define OUTH 7
#define OUTW 7
#define TS 32            // tile edge
#define NT 16            // tiles per dim = 512/32
#define CG 64            // channels per K1 block
#define NROI_BINS (OUTH * OUTW)

typedef float f32x4 __attribute__((ext_vector_type(4)));

static constexpr size_t SLOC_ELEMS = (size_t)Hdim * Wdim * Cdim;   // ~268 MB
static constexpr size_t EL_ELEMS   = (size_t)Hdim * NT * Cdim;     // ~8.4 MB
static constexpr size_t F_ELEMS    = (size_t)NT * Wdim * Cdim;     // ~8.4 MB
static constexpr size_t WS_NEED    = (SLOC_ELEMS + EL_ELEMS + F_ELEMS) * sizeof(float);

// ---------------- K1: per-tile local 2D SAT (32x32 tiles) -------------------
__global__ void local_sat(const float* __restrict__ x, float* __restrict__ Sloc) {
    const int cg = blockIdx.x & 3;
    const int tJ = (blockIdx.x >> 2) & (NT - 1);
    const int tI = blockIdx.x >> 6;
    const int c  = cg * CG + threadIdx.x;

    const size_t base = ((size_t)(tI * TS) * Wdim + (size_t)(tJ * TS)) * Cdim + c;
    const float* xp = x + base;
    float* sp = Sloc + base;

    float P[TS];
    #pragma unroll
    for (int w = 0; w < TS; ++w) P[w] = 0.f;

    float va[TS], vb[TS];
    #pragma unroll
    for (int w = 0; w < TS; ++w) va[w] = xp[(size_t)w * Cdim];   // row 0

    #pragma unroll
    for (int h = 0; h < TS; ++h) {
        const float* cur = (h & 1) ? vb : va;
        float*       nxt = (h & 1) ? va : vb;
        if (h + 1 < TS) {
            #pragma unroll
            for (int w = 0; w < TS; ++w)
                nxt[w] = xp[((size_t)(h + 1) * Wdim + w) * Cdim];
        }
        float rowAcc = 0.f;
        #pragma unroll
        for (int w = 0; w < TS; ++w) {
            rowAcc += cur[w];
            P[w] += rowAcc;
            sp[((size_t)h * Wdim + w) * Cdim] = P[w];
        }
    }
}

// ---------------- K2a: E_left[h][J][c] = sum_{J'<J} Sloc[h][32J'+31][c] -----
__global__ void make_eleft(const float* __restrict__ Sloc, float* __restrict__ EL) {
    const int h = blockIdx.x;
    const int c = threadIdx.x;
    const float* sp = Sloc + (size_t)h * Wdim * Cdim + c;
    float* ep = EL + (size_t)h * NT * Cdim + c;

    double acc = 0.0;
    #pragma unroll
    for (int J = 0; J < NT; ++J) {
        const float t = sp[(size_t)(J * TS + TS - 1) * Cdim];
        ep[(size_t)J * Cdim] = (float)acc;
        acc += (double)t;
    }
}

// ---------------- K2b: F[I][w][c] = sum_{I'<I} (Sloc[32I'+31][w][c]
//                                               + EL[32I'+31][w>>5][c]) ------
__global__ void make_f(const float* __restrict__ Sloc, const float* __restrict__ EL,
                       float* __restrict__ F) {
    const int w = blockIdx.x;
    const int c = threadIdx.x;
    const int J = w >> 5;
    const float* sp = Sloc + (size_t)w * Cdim + c;
    const float* ep = EL + (size_t)J * Cdim + c;
    float* fp = F + (size_t)w * Cdim + c;

    double acc = 0.0;
    #pragma unroll
    for (int I = 0; I < NT; ++I) {
        const int hb = I * TS + TS - 1;
        const float a = sp[(size_t)hb * Wdim * Cdim];
        const float b = ep[(size_t)hb * NT * Cdim];
        fp[(size_t)I * Wdim * Cdim] = (float)acc;
        acc += (double)a + (double)b;
    }
}

// ---------------- shared bin-edge math (replicates reference exactly) ------
__device__ __forceinline__ void roi_bounds(const float4 r, int& hs, int& ws,
                                           int& rh, int& rw) {
    hs = (int)floorf((float)Hdim * r.x);
    ws = (int)floorf((float)Wdim * r.y);
    int he = (int)floorf((float)Hdim * r.z);
    int we = (int)floorf((float)Wdim * r.w);
    he = max(he, hs + 1);
    we = max(we, ws + 1);
    rh = he - hs;
    rw = we - ws;
}

// float4-quad corner of padded integral image at (hb, wb), channel quad q.
__device__ __forceinline__ f32x4 corner4(const f32x4* __restrict__ Sloc,
                                         const f32x4* __restrict__ EL,
                                         const f32x4* __restrict__ F,
                                         int hb, int wb, int q) {
    f32x4 z = {0.f, 0.f, 0.f, 0.f};
    if (hb == 0 || wb == 0) return z;
    const int h = hb - 1, w = wb - 1;
    const int I = h >> 5, J = w >> 5;
    const f32x4 s = __builtin_nontemporal_load(&Sloc[((size_t)h * Wdim + w) * CQ + q]);
    const f32x4 f = F[((size_t)I * Wdim + w) * CQ + q];
    const f32x4 e = EL[((size_t)h * NT + J) * CQ + q];
    return s + f + e;
}

// ---------------- K3: gather, block = one ROI, float4 channels --------------
// 256 threads: sub = t>>6 handles out-rows i in {sub, sub+4}; q = t&63 is the
// float4 channel quad. 12 independent 16B loads per (i,j), j fully
// unrolled -> deep ILP.
__global__ __launch_bounds__(256) void gather_kernel(
        const f32x4* __restrict__ Sloc, const f32x4* __restrict__ EL,
        const f32x4* __restrict__ F, const float4* __restrict__ rois,
        f32x4* __restrict__ out, int N) {
    const int n   = blockIdx.x;
    const int sub = threadIdx.x >> 6;
    const int q   = threadIdx.x & 63;

    const float4 r = rois[n];   // y0,x0,y1,x1
    int hs, ws, rh, rw;
    roi_bounds(r, hs, ws, rh, rw);

    // precompute w edges once (reused by both i's)
    int wb0a[OUTW], wb1a[OUTW];
    #pragma unroll
    for (int j = 0; j < OUTW; ++j) {
        wb0a[j] = ws + (j * rw) / OUTW;
        wb1a[j] = ws + ((j + 1) * rw + OUTW - 1) / OUTW;
    }

    #pragma unroll
    for (int ii = 0; ii < 2; ++ii) {
        const int i = sub + ii * 4;
        if (i >= OUTH) break;     // sub==3, ii==1

        const int hb0 = hs + (i * rh) / OUTH;
        const int hb1 = hs + ((i + 1) * rh + OUTH - 1) / OUTH;
        const float dh = (float)(hb1 - hb0);

        f32x4* op = out + ((size_t)(n * OUTH + i) * OUTW) * CQ + q;

        #pragma unroll
        for (int j = 0; j < OUTW; ++j) {
            const int wb0 = wb0a[j], wb1 = wb1a[j];
            const f32x4 s11 = corner4(Sloc, EL, F, hb1, wb1, q);
            const f32x4 s01 = corner4(Sloc, EL, F, hb0, wb1, q);
            const f32x4 s10 = corner4(Sloc, EL, F, hb1, wb0, q);
            const f32x4 s00 = corner4(Sloc, EL, F, hb0, wb0, q);
            const float inv = 1.0f / (dh * (float)(wb1 - wb0));
            const f32x4 o = (((s11 - s01) - s10) + s00) * inv;
            __builtin_nontemporal_store(o, &op[(size_t)j * CQ]);
        }
    }
}

// ---------------- Fallback: direct per-bin summation (ws too small) --------
__global__ void direct_kernel(const float* __restrict__ x,
                              const float* __restrict__ rois,
                              float* __restrict__ out, int N) {
    const int bid = blockIdx.x;
    const int n = bid / NROI_BINS;
    const int rem = bid % NROI_BINS;
    const int i = rem / OUTW;
    const int j = rem % OUTW;
    const int c = threadIdx.x;
    if (n >= N) return;

    const float4 r = reinterpret_cast<const float4*>(rois)[n];
    int hs, ws, rh, rw;
    roi_bounds(r, hs, ws, rh, rw);

    const int hb0 = hs + (i * rh) / OUTH;
    const int hb1 = hs + ((i + 1) * rh + OUTH - 1) / OUTH;
    const int wb0 = ws + (j * rw) / OUTW;
    const int wb1 = ws + ((j + 1) * rw + OUTW - 1) / OUTW;

    double acc = 0.0;
    for (int h = hb0; h < hb1; ++h) {
        const float* xp = x + ((size_t)h * Wdim) * Cdim + c;
        for (int w = wb0; w < wb1; ++w)
            acc += (double)xp[(size_t)w * Cdim];
    }
    const float area = (float)((hb1 - hb0) * (wb1 - wb0));
    out[((size_t)bid) * Cdim + c] = (float)(acc / (double)area);
}

extern "C" void kernel_launch(void* const* d_in, const int* in_sizes, int n_in,
                              void* d_out, int out_size, void* d_ws, size_t ws_size,
                              hipStream_t stream) {
    const float* x    = (const float*)d_in[0];
    const float* rois = (const float*)d_in[1];
    float* out        = (float*)d_out;
    const int N       = in_sizes[1] / 4;   // 2000

    if (ws_size >= WS_NEED) {
        float* Sloc = (float*)d_ws;
        float* EL   = Sloc + SLOC_ELEMS;
        float* F    = EL + EL_ELEMS;
        local_sat<<<NT * NT * 4, CG, 0, stream>>>(x, Sloc);
        make_eleft<<<Hdim, Cdim, 0, stream>>>(Sloc, EL);
        make_f<<<Wdim, Cdim, 0, stream>>>(Sloc, EL, F);
        gather_kernel<<<N, 256, 0, stream>>>(
            (const f32x4*)Sloc, (const f32x4*)EL, (const f32x4*)F,
            (const float4*)rois, (f32x4*)out, N);
    } else {
        direct_kernel<<<N * NROI_BINS, Cdim, 0, stream>>>(x, rois, out, N);
    }
}

// Round 7
// 231.341 us; speedup vs baseline: 1.4015x; 1.0257x over previous
//
#include <hip/hip_runtime.h>

#define Hdim 512
#define Wdim 512
#define Cdim 256
#define CQ 64            // Cdim/4 float4 quads per line
#define OUTH 7
#define OUTW 7
#define TS 32            // tile edge
#define NT 16            // tiles per dim = 512/32
#define CG 64            // channels per K1 block
#define NROI_BINS (OUTH * OUTW)

typedef float f32x4 __attribute__((ext_vector_type(4)));

static constexpr size_t SLOC_ELEMS = (size_t)Hdim * Wdim * Cdim;   // ~268 MB
static constexpr size_t EL_ELEMS   = (size_t)Hdim * NT * Cdim;     // ~8.4 MB
static constexpr size_t F_ELEMS    = (size_t)NT * Wdim * Cdim;     // ~8.4 MB
static constexpr size_t WS_NEED    = (SLOC_ELEMS + EL_ELEMS + F_ELEMS) * sizeof(float);

// ---------------- K1: per-tile local 2D SAT (32x32 tiles) -------------------
__global__ void local_sat(const float* __restrict__ x, float* __restrict__ Sloc) {
    const int cg = blockIdx.x & 3;
    const int tJ = (blockIdx.x >> 2) & (NT - 1);
    const int tI = blockIdx.x >> 6;
    const int c  = cg * CG + threadIdx.x;

    const size_t base = ((size_t)(tI * TS) * Wdim + (size_t)(tJ * TS)) * Cdim + c;
    const float* xp = x + base;
    float* sp = Sloc + base;

    float P[TS];
    #pragma unroll
    for (int w = 0; w < TS; ++w) P[w] = 0.f;

    float va[TS], vb[TS];
    #pragma unroll
    for (int w = 0; w < TS; ++w) va[w] = xp[(size_t)w * Cdim];   // row 0

    #pragma unroll
    for (int h = 0; h < TS; ++h) {
        const float* cur = (h & 1) ? vb : va;
        float*       nxt = (h & 1) ? va : vb;
        if (h + 1 < TS) {
            #pragma unroll
            for (int w = 0; w < TS; ++w)
                nxt[w] = xp[((size_t)(h + 1) * Wdim + w) * Cdim];
        }
        float rowAcc = 0.f;
        #pragma unroll
        for (int w = 0; w < TS; ++w) {
            rowAcc += cur[w];
            P[w] += rowAcc;
            sp[((size_t)h * Wdim + w) * Cdim] = P[w];
        }
    }
}

// ---------------- K2a: E_left[h][J][c] = sum_{J'<J} Sloc[h][32J'+31][c] -----
__global__ void make_eleft(const float* __restrict__ Sloc, float* __restrict__ EL) {
    const int h = blockIdx.x;
    const int c = threadIdx.x;
    const float* sp = Sloc + (size_t)h * Wdim * Cdim + c;
    float* ep = EL + (size_t)h * NT * Cdim + c;

    double acc = 0.0;
    #pragma unroll
    for (int J = 0; J < NT; ++J) {
        const float t = sp[(size_t)(J * TS + TS - 1) * Cdim];
        ep[(size_t)J * Cdim] = (float)acc;
        acc += (double)t;
    }
}

// ---------------- K2b: F[I][w][c] = sum_{I'<I} (Sloc[32I'+31][w][c]
//                                               + EL[32I'+31][w>>5][c]) ------
__global__ void make_f(const float* __restrict__ Sloc, const float* __restrict__ EL,
                       float* __restrict__ F) {
    const int w = blockIdx.x;
    const int c = threadIdx.x;
    const int J = w >> 5;
    const float* sp = Sloc + (size_t)w * Cdim + c;
    const float* ep = EL + (size_t)J * Cdim + c;
    float* fp = F + (size_t)w * Cdim + c;

    double acc = 0.0;
    #pragma unroll
    for (int I = 0; I < NT; ++I) {
        const int hb = I * TS + TS - 1;
        const float a = sp[(size_t)hb * Wdim * Cdim];
        const float b = ep[(size_t)hb * NT * Cdim];
        fp[(size_t)I * Wdim * Cdim] = (float)acc;
        acc += (double)a + (double)b;
    }
}

// ---------------- shared bin-edge math (replicates reference exactly) ------
__device__ __forceinline__ void roi_bounds(const float4 r, int& hs, int& ws,
                                           int& rh, int& rw) {
    hs = (int)floorf((float)Hdim * r.x);
    ws = (int)floorf((float)Wdim * r.y);
    int he = (int)floorf((float)Hdim * r.z);
    int we = (int)floorf((float)Wdim * r.w);
    he = max(he, hs + 1);
    we = max(we, ws + 1);
    rh = he - hs;
    rw = we - ws;
}

// ---------------- K3: gather, one wave per (roi, out-row) -------------------
// 64 threads; lane = channel quad. All loads unconditional (clamped index +
// multiplicative mask) so the scheduler can batch NT loads across the fully
// unrolled j loop.
__global__ __launch_bounds__(64, 4) void gather_kernel(
        const f32x4* __restrict__ Sloc, const f32x4* __restrict__ EL,
        const f32x4* __restrict__ F, const float4* __restrict__ rois,
        f32x4* __restrict__ out, int N) {
    const int b = blockIdx.x;
    const int n = b / OUTH;
    const int i = b - n * OUTH;
    const int q = threadIdx.x;      // 0..63

    const float4 r = rois[n];       // y0,x0,y1,x1
    int hs, ws, rh, rw;
    roi_bounds(r, hs, ws, rh, rw);

    const int hb0 = hs + (i * rh) / OUTH;
    const int hb1 = hs + ((i + 1) * rh + OUTH - 1) / OUTH;   // ceil div
    const float dh = (float)(hb1 - hb0);

    const int  h1 = hb1 - 1;                 // hb1 >= 1 always
    const int  h0 = max(hb0 - 1, 0);
    const float mh0 = (hb0 > 0) ? 1.f : 0.f;
    const int  I1 = h1 >> 5, I0 = h0 >> 5;

    f32x4* op = out + ((size_t)(n * OUTH + i) * OUTW) * CQ + q;

    #pragma unroll
    for (int j = 0; j < OUTW; ++j) {
        const int wb0 = ws + (j * rw) / OUTW;
        const int wb1 = ws + ((j + 1) * rw + OUTW - 1) / OUTW;
        const int w1 = wb1 - 1;              // wb1 >= 1 always
        const int w0 = max(wb0 - 1, 0);
        const float mw0 = (wb0 > 0) ? 1.f : 0.f;
        const int J1 = w1 >> 5, J0 = w0 >> 5;

        // 4 NT Sloc loads — unconditional
        const f32x4 a11 = __builtin_nontemporal_load(&Sloc[((size_t)h1 * Wdim + w1) * CQ + q]);
        const f32x4 a01 = __builtin_nontemporal_load(&Sloc[((size_t)h0 * Wdim + w1) * CQ + q]);
        const f32x4 a10 = __builtin_nontemporal_load(&Sloc[((size_t)h1 * Wdim + w0) * CQ + q]);
        const f32x4 a00 = __builtin_nontemporal_load(&Sloc[((size_t)h0 * Wdim + w0) * CQ + q]);
        // F / EL (L2/L3-hot)
        const f32x4 f11 = F[((size_t)I1 * Wdim + w1) * CQ + q];
        const f32x4 f01 = F[((size_t)I0 * Wdim + w1) * CQ + q];
        const f32x4 f10 = F[((size_t)I1 * Wdim + w0) * CQ + q];
        const f32x4 f00 = F[((size_t)I0 * Wdim + w0) * CQ + q];
        const f32x4 e11 = EL[((size_t)h1 * NT + J1) * CQ + q];
        const f32x4 e01 = EL[((size_t)h0 * NT + J1) * CQ + q];
        const f32x4 e10 = EL[((size_t)h1 * NT + J0) * CQ + q];
        const f32x4 e00 = EL[((size_t)h0 * NT + J0) * CQ + q];

        const f32x4 s11 = a11 + f11 + e11;
        const f32x4 s01 = (a01 + f01 + e01) * mh0;
        const f32x4 s10 = (a10 + f10 + e10) * mw0;
        const f32x4 s00 = (a00 + f00 + e00) * (mh0 * mw0);

        const float inv = 1.0f / (dh * (float)(wb1 - wb0));
        const f32x4 o = (((s11 - s01) - s10) + s00) * inv;
        __builtin_nontemporal_store(o, &op[(size_t)j * CQ]);
    }
}

// ---------------- Fallback: direct per-bin summation (ws too small) --------
__global__ void direct_kernel(const float* __restrict__ x,
                              const float* __restrict__ rois,
                              float* __restrict__ out, int N) {
    const int bid = blockIdx.x;
    const int n = bid / NROI_BINS;
    const int rem = bid % NROI_BINS;
    const int i = rem / OUTW;
    const int j = rem % OUTW;
    const int c = threadIdx.x;
    if (n >= N) return;

    const float4 r = reinterpret_cast<const float4*>(rois)[n];
    int hs, ws, rh, rw;
    roi_bounds(r, hs, ws, rh, rw);

    const int hb0 = hs + (i * rh) / OUTH;
    const int hb1 = hs + ((i + 1) * rh + OUTH - 1) / OUTH;
    const int wb0 = ws + (j * rw) / OUTW;
    const int wb1 = ws + ((j + 1) * rw + OUTW - 1) / OUTW;

    double acc = 0.0;
    for (int h = hb0; h < hb1; ++h) {
        const float* xp = x + ((size_t)h * Wdim) * Cdim + c;
        for (int w = wb0; w < wb1; ++w)
            acc += (double)xp[(size_t)w * Cdim];
    }
    const float area = (float)((hb1 - hb0) * (wb1 - wb0));
    out[((size_t)bid) * Cdim + c] = (float)(acc / (double)area);
}

extern "C" void kernel_launch(void* const* d_in, const int* in_sizes, int n_in,
                              void* d_out, int out_size, void* d_ws, size_t ws_size,
                              hipStream_t stream) {
    const float* x    = (const float*)d_in[0];
    const float* rois = (const float*)d_in[1];
    float* out        = (float*)d_out;
    const int N       = in_sizes[1] / 4;   // 2000

    if (ws_size >= WS_NEED) {
        float* Sloc = (float*)d_ws;
        float* EL   = Sloc + SLOC_ELEMS;
        float* F    = EL + EL_ELEMS;
        local_sat<<<NT * NT * 4, CG, 0, stream>>>(x, Sloc);
        make_eleft<<<Hdim, Cdim, 0, stream>>>(Sloc, EL);
        make_f<<<Wdim, Cdim, 0, stream>>>(Sloc, EL, F);
        gather_kernel<<<N * OUTH, 64, 0, stream>>>(
            (const f32x4*)Sloc, (const f32x4*)EL, (const f32x4*)F,
            (const float4*)rois, (f32x4*)out, N);
    } else {
        direct_kernel<<<N * NROI_BINS, Cdim, 0, stream>>>(x, rois, out, N);
    }
}